// Round 1
// baseline (739.972 us; speedup 1.0000x reference)
//
#include <hip/hip_runtime.h>
#include <stdint.h>

#define NN 100000
#define EE 1600000
#define FF 128
#define CAP 64   // max tracked in-degree; Poisson(16) => P(deg>=64) ~ 2e-18

__device__ __forceinline__ float bf2f(unsigned short u) {
    union { unsigned int i; float f; } c; c.i = ((unsigned int)u) << 16; return c.f;
}
__device__ __forceinline__ unsigned short f2bf(float f) {
    union { unsigned int i; float f; } c; c.f = f;
    unsigned int u = c.i;
    return (unsigned short)((u + 0x7FFFu + ((u >> 16) & 1u)) >> 16);
}

// ---------------- GEMM1: qkvs = nodes @ [Wq|Wk|Wv|Wskip] + bias, bf16 out ----
// 16 rows/block, 256 threads: each thread does 2 output cols x 16 rows.
__global__ __launch_bounds__(256) void k_qkvs(
    const float* __restrict__ nodes,
    const float* __restrict__ Wq, const float* __restrict__ bq,
    const float* __restrict__ Wk, const float* __restrict__ bk,
    const float* __restrict__ Wv, const float* __restrict__ bv,
    const float* __restrict__ Ws, const float* __restrict__ bs,
    unsigned short* __restrict__ oq, unsigned short* __restrict__ ok,
    unsigned short* __restrict__ ov, unsigned short* __restrict__ os)
{
    __shared__ float a[16][FF];
    const int tid = threadIdx.x;
    const size_t row0 = (size_t)blockIdx.x * 16;
    const float* gsrc = nodes + row0 * FF;
    #pragma unroll
    for (int u = 0; u < 8; ++u) {
        int idx = tid + 256 * u;
        ((float*)a)[idx] = gsrc[idx];
    }
    __syncthreads();

    const int col = tid & 127;
    const bool lo = tid < 128;
    const float* W0 = lo ? Wq : Wk;
    const float* B0 = lo ? bq : bk;
    unsigned short* O0 = lo ? oq : ok;
    const float* W1 = lo ? Wv : Ws;
    const float* B1 = lo ? bv : bs;
    unsigned short* O1 = lo ? ov : os;

    float acc0[16], acc1[16];
    #pragma unroll
    for (int r = 0; r < 16; ++r) { acc0[r] = 0.f; acc1[r] = 0.f; }

    #pragma unroll 2
    for (int kk = 0; kk < FF; ++kk) {
        float w0 = W0[kk * FF + col];
        float w1 = W1[kk * FF + col];
        #pragma unroll
        for (int r = 0; r < 16; ++r) {
            float av = a[r][kk];
            acc0[r] = fmaf(av, w0, acc0[r]);
            acc1[r] = fmaf(av, w1, acc1[r]);
        }
    }
    const float b0 = B0[col], b1 = B1[col];
    #pragma unroll
    for (int r = 0; r < 16; ++r) {
        size_t off = (row0 + r) * FF + col;
        O0[off] = f2bf(acc0[r] + b0);
        O1[off] = f2bf(acc1[r] + b1);
    }
}

// ---------------- build per-dst bucket lists ---------------------------------
__global__ __launch_bounds__(256) void k_build(
    const int* __restrict__ src, const int* __restrict__ dst,
    int* __restrict__ count, int* __restrict__ srclist)
{
    int e = blockIdx.x * 256 + threadIdx.x;
    if (e >= EE) return;
    int d = dst[e];
    int s = src[e];
    int r = atomicAdd(&count[d], 1);
    if (r < CAP) srclist[(size_t)d * CAP + r] = s;
}

// ---------------- per-destination attention (1 wave per node) ----------------
// lane l holds feature dims {2l, 2l+1}; lanes 0..31 = head0, 32..63 = head1.
// x (= agg + skip) is written over the skip buffer (same thread r/w, safe).
__global__ __launch_bounds__(256) void k_attn(
    const unsigned short* __restrict__ q, const unsigned short* __restrict__ k,
    const unsigned short* __restrict__ v, unsigned short* __restrict__ skx,
    const int* __restrict__ count, const int* __restrict__ srclist)
{
    const int wid = (int)((blockIdx.x * 256 + threadIdx.x) >> 6);
    if (wid >= NN) return;
    const int lane = threadIdx.x & 63;

    const ushort2 qr = *(const ushort2*)(q + (size_t)wid * FF + 2 * lane);
    const float qa = bf2f(qr.x), qb = bf2f(qr.y);

    int deg = __builtin_amdgcn_readfirstlane(count[wid]);
    if (deg > CAP) deg = CAP;
    const size_t base = (size_t)wid * CAP;

    float denom = 0.f, acc0 = 0.f, acc1 = 0.f;
    for (int e = 0; e < deg; ++e) {
        const int s = __builtin_amdgcn_readfirstlane(srclist[base + e]);
        const ushort2 kr = *(const ushort2*)(k + (size_t)s * FF + 2 * lane);
        float p = qa * bf2f(kr.x) + qb * bf2f(kr.y);
        p += __shfl_xor(p, 1);
        p += __shfl_xor(p, 2);
        p += __shfl_xor(p, 4);
        p += __shfl_xor(p, 8);
        p += __shfl_xor(p, 16);          // 32-lane half-sum = per-head logit
        const float ex = __expf(p * 0.125f);   // 1/sqrt(64)
        const ushort2 vr = *(const ushort2*)(v + (size_t)s * FF + 2 * lane);
        denom += ex;
        acc0 = fmaf(ex, bf2f(vr.x), acc0);
        acc1 = fmaf(ex, bf2f(vr.y), acc1);
    }
    const float inv = (denom > 0.f) ? (1.0f / denom) : 0.f;
    const ushort2 sr = *(const ushort2*)(skx + (size_t)wid * FF + 2 * lane);
    const float x0 = fmaf(acc0, inv, bf2f(sr.x));
    const float x1 = fmaf(acc1, inv, bf2f(sr.y));
    ushort2 o; o.x = f2bf(x0); o.y = f2bf(x1);
    *(ushort2*)(skx + (size_t)wid * FF + 2 * lane) = o;
}

// ---------------- GEMM2 + epilogue: gate/fuse/out ----------------------------
__global__ __launch_bounds__(256) void k_out(
    const float* __restrict__ nodes, const unsigned short* __restrict__ x,
    const float* __restrict__ Wg, const float* __restrict__ Wf,
    float* __restrict__ out)
{
    __shared__ float an[16][FF];
    __shared__ float ax[16][FF];
    const int tid = threadIdx.x;
    const size_t row0 = (size_t)blockIdx.x * 16;
    #pragma unroll
    for (int u = 0; u < 8; ++u) {
        int idx = tid + 256 * u;
        ((float*)an)[idx] = nodes[row0 * FF + idx];
        ((float*)ax)[idx] = bf2f(x[row0 * FF + idx]);
    }
    __syncthreads();

    const int j = tid & 127;
    const int rg = tid >> 7;      // 0/1 -> rows rg*8 .. rg*8+7
    float gacc[8], facc[8];
    #pragma unroll
    for (int r = 0; r < 8; ++r) { gacc[r] = 0.f; facc[r] = 0.f; }

    #pragma unroll 2
    for (int kk = 0; kk < FF; ++kk) {
        const float wg1 = Wg[kk * FF + j];
        const float wg2 = Wg[(FF + kk) * FF + j];
        const float wf  = Wf[kk * FF + j];
        #pragma unroll
        for (int r = 0; r < 8; ++r) {
            const float nv = an[rg * 8 + r][kk];
            const float xv = ax[rg * 8 + r][kk];
            gacc[r] = fmaf(nv, wg1, gacc[r]);
            gacc[r] = fmaf(xv, wg2, gacc[r]);
            facc[r] = fmaf(xv, wf,  facc[r]);
        }
    }
    #pragma unroll
    for (int r = 0; r < 8; ++r) {
        const int rr = rg * 8 + r;
        const float g = 1.0f / (1.0f + __expf(-gacc[r]));
        const float f = tanhf(facc[r]);
        out[(row0 + rr) * FF + j] = g * f + (1.0f - g) * an[rr][j];
    }
}

extern "C" void kernel_launch(void* const* d_in, const int* in_sizes, int n_in,
                              void* d_out, int out_size, void* d_ws, size_t ws_size,
                              hipStream_t stream) {
    const float* nodes = (const float*)d_in[0];
    const int*   ei    = (const int*)d_in[1];
    const int*   esrc  = ei;        // edge_index[0]
    const int*   edst  = ei + EE;   // edge_index[1]
    const float* Wq = (const float*)d_in[2];
    const float* bq = (const float*)d_in[3];
    const float* Wk = (const float*)d_in[4];
    const float* bk = (const float*)d_in[5];
    const float* Wv = (const float*)d_in[6];
    const float* bv = (const float*)d_in[7];
    const float* Ws = (const float*)d_in[8];
    const float* bs = (const float*)d_in[9];
    const float* Wg = (const float*)d_in[10];
    const float* Wf = (const float*)d_in[11];
    float* out = (float*)d_out;

    // ws layout (bytes):
    //   q   : NN*FF*2 = 25.6MB
    //   k   : 25.6MB
    //   v   : 25.6MB
    //   skx : 25.6MB   (skip, overwritten with x)
    //   count: NN*4 = 0.4MB
    //   srclist: NN*CAP*4 = 25.6MB
    unsigned short* q   = (unsigned short*)d_ws;
    unsigned short* k   = q + (size_t)NN * FF;
    unsigned short* v   = k + (size_t)NN * FF;
    unsigned short* skx = v + (size_t)NN * FF;
    int* count   = (int*)(skx + (size_t)NN * FF);
    int* srclist = count + NN;

    hipMemsetAsync(count, 0, NN * sizeof(int), stream);

    k_qkvs<<<NN / 16, 256, 0, stream>>>(nodes, Wq, bq, Wk, bk, Wv, bv, Ws, bs,
                                        q, k, v, skx);
    k_build<<<(EE + 255) / 256, 256, 0, stream>>>(esrc, edst, count, srclist);
    k_attn<<<(NN * 64) / 256, 256, 0, stream>>>(q, k, v, skx, count, srclist);
    k_out<<<NN / 16, 256, 0, stream>>>(nodes, skx, Wg, Wf, out);
}

// Round 2
// 528.674 us; speedup vs baseline: 1.3997x; 1.3997x over previous
//
#include <hip/hip_runtime.h>
#include <stdint.h>

#define NN 100000
#define EE 1600000
#define FF 128
#define NQ 512   // q|k|v|skip interleaved width
#define CAP 60   // max tracked in-degree; Poisson(16) => P(deg>=60) ~ 1e-14

typedef __attribute__((ext_vector_type(8)))  short bf16x8;
typedef __attribute__((ext_vector_type(16))) float f32x16;

__device__ __forceinline__ float bf2f(unsigned short u) {
    union { unsigned int i; float f; } c; c.i = ((unsigned int)u) << 16; return c.f;
}
__device__ __forceinline__ unsigned short f2bf(float f) {
    union { unsigned int i; float f; } c; c.f = f;
    unsigned int u = c.i;
    return (unsigned short)((u + 0x7FFFu + ((u >> 16) & 1u)) >> 16);
}
__device__ __forceinline__ bf16x8 pack8(const float* p) {
    float4 f0 = *(const float4*)p;
    float4 f1 = *(const float4*)(p + 4);
    bf16x8 r;
    r[0] = (short)f2bf(f0.x); r[1] = (short)f2bf(f0.y);
    r[2] = (short)f2bf(f0.z); r[3] = (short)f2bf(f0.w);
    r[4] = (short)f2bf(f1.x); r[5] = (short)f2bf(f1.y);
    r[6] = (short)f2bf(f1.z); r[7] = (short)f2bf(f1.w);
    return r;
}

// ---------------- prep: transpose weights to [col][k] bf16, concat biases ---
// Wt   : [512][128]  (cols 0-127=Wq, 128-255=Wk, 256-383=Wv, 384-511=Wskip)
// Wg1t : [128][128]  (Wgate rows 0-127,   transposed)
// Wg2t : [128][128]  (Wgate rows 128-255, transposed)
// Wft  : [128][128]
// bias : [512] f32
__global__ __launch_bounds__(256) void k_prep(
    const float* __restrict__ Wq, const float* __restrict__ Wk,
    const float* __restrict__ Wv, const float* __restrict__ Ws,
    const float* __restrict__ Wg, const float* __restrict__ Wf,
    const float* __restrict__ bq, const float* __restrict__ bk,
    const float* __restrict__ bv, const float* __restrict__ bs,
    unsigned short* __restrict__ Wt, unsigned short* __restrict__ Wg1t,
    unsigned short* __restrict__ Wg2t, unsigned short* __restrict__ Wft,
    float* __restrict__ bias)
{
    int idx = blockIdx.x * 256 + threadIdx.x;
    if (idx < 65536) {
        int col = idx >> 7, k = idx & 127;
        int seg = col >> 7, c = col & 127;
        const float* W = (seg == 0) ? Wq : (seg == 1) ? Wk : (seg == 2) ? Wv : Ws;
        Wt[idx] = f2bf(W[k * FF + c]);
    } else if (idx < 81920) {
        int j = idx - 65536; int col = j >> 7, k = j & 127;
        Wg1t[j] = f2bf(Wg[k * FF + col]);
    } else if (idx < 98304) {
        int j = idx - 81920; int col = j >> 7, k = j & 127;
        Wg2t[j] = f2bf(Wg[(FF + k) * FF + col]);
    } else if (idx < 114688) {
        int j = idx - 98304; int col = j >> 7, k = j & 127;
        Wft[j] = f2bf(Wf[k * FF + col]);
    } else if (idx < 115200) {
        int j = idx - 114688;
        float b = (j < 128) ? bq[j] : (j < 256) ? bk[j - 128]
                : (j < 384) ? bv[j - 256] : bs[j - 384];
        bias[j] = b;
    }
}

// ---------------- GEMM1 (MFMA): qkvs = nodes @ [Wq|Wk|Wv|Ws] + b, bf16 out --
// wave = 32 rows x 512 cols (4 col-groups of 128, sequential).
// A frags direct from global fp32 (converted), B frags from transposed Wt.
__global__ __launch_bounds__(256) void k_qkvs(
    const float* __restrict__ nodes, const unsigned short* __restrict__ Wt,
    const float* __restrict__ bias, unsigned short* __restrict__ qkvs)
{
    const int wave = threadIdx.x >> 6, lane = threadIdx.x & 63;
    const int row0 = (blockIdx.x * 4 + wave) * 32;
    if (row0 >= NN) return;
    const int arow  = row0 + (lane & 31);
    const int khalf = lane >> 5;                 // 0/1 -> k offset 0/8

    bf16x8 afr[8];                               // K=128 in 8 steps of 16
    const float* ap = nodes + (size_t)arow * FF + khalf * 8;
    #pragma unroll
    for (int ks = 0; ks < 8; ++ks) afr[ks] = pack8(ap + ks * 16);

    #pragma unroll 1
    for (int cg = 0; cg < 4; ++cg) {
        f32x16 acc[4];
        #pragma unroll
        for (int cf = 0; cf < 4; ++cf)
            #pragma unroll
            for (int r = 0; r < 16; ++r) acc[cf][r] = 0.f;

        #pragma unroll
        for (int ks = 0; ks < 8; ++ks) {
            #pragma unroll
            for (int cf = 0; cf < 4; ++cf) {
                const int col = cg * 128 + cf * 32 + (lane & 31);
                bf16x8 b = *(const bf16x8*)(Wt + (size_t)col * FF + ks * 16 + khalf * 8);
                acc[cf] = __builtin_amdgcn_mfma_f32_32x32x16_bf16(afr[ks], b, acc[cf], 0, 0, 0);
            }
        }
        #pragma unroll
        for (int cf = 0; cf < 4; ++cf) {
            const int col = cg * 128 + cf * 32 + (lane & 31);
            const float bv = bias[col];
            #pragma unroll
            for (int r = 0; r < 16; ++r) {
                const int rr = row0 + (r & 3) + 8 * (r >> 2) + 4 * (lane >> 5);
                qkvs[(size_t)rr * NQ + col] = f2bf(acc[cf][r] + bv);
            }
        }
    }
}

// ---------------- build per-dst bucket lists ---------------------------------
__global__ __launch_bounds__(256) void k_build(
    const int* __restrict__ src, const int* __restrict__ dst,
    int* __restrict__ count, int* __restrict__ srclist)
{
    int e = blockIdx.x * 256 + threadIdx.x;
    if (e >= EE) return;
    int d = dst[e];
    int s = src[e];
    int r = atomicAdd(&count[d], 1);
    if (r < CAP) srclist[(size_t)d * CAP + r] = s;
}

// ---------------- per-destination attention (1 wave per node) ----------------
// qkvs row layout: [0,128)=q, [128,256)=k, [256,384)=v, [384,512)=skip->x
__global__ __launch_bounds__(256) void k_attn(
    unsigned short* __restrict__ qkvs,
    const int* __restrict__ count, const int* __restrict__ srclist)
{
    const int wid = (int)((blockIdx.x * 256 + threadIdx.x) >> 6);
    if (wid >= NN) return;
    const int lane = threadIdx.x & 63;

    const ushort2 qr = *(const ushort2*)(qkvs + (size_t)wid * NQ + 2 * lane);
    const float qa = bf2f(qr.x), qb = bf2f(qr.y);

    int deg = __builtin_amdgcn_readfirstlane(count[wid]);
    if (deg > CAP) deg = CAP;
    const size_t base = (size_t)wid * CAP;

    float denom = 0.f, acc0 = 0.f, acc1 = 0.f;
    for (int e = 0; e < deg; ++e) {
        const int s = __builtin_amdgcn_readfirstlane(srclist[base + e]);
        const ushort2 kr = *(const ushort2*)(qkvs + (size_t)s * NQ + 128 + 2 * lane);
        float p = qa * bf2f(kr.x) + qb * bf2f(kr.y);
        p += __shfl_xor(p, 1);
        p += __shfl_xor(p, 2);
        p += __shfl_xor(p, 4);
        p += __shfl_xor(p, 8);
        p += __shfl_xor(p, 16);          // 32-lane half-sum = per-head logit
        const float ex = __expf(p * 0.125f);   // 1/sqrt(64)
        const ushort2 vr = *(const ushort2*)(qkvs + (size_t)s * NQ + 256 + 2 * lane);
        denom += ex;
        acc0 = fmaf(ex, bf2f(vr.x), acc0);
        acc1 = fmaf(ex, bf2f(vr.y), acc1);
    }
    const float inv = (denom > 0.f) ? (1.0f / denom) : 0.f;
    unsigned short* sx = qkvs + (size_t)wid * NQ + 384 + 2 * lane;
    const ushort2 sr = *(const ushort2*)sx;
    ushort2 o;
    o.x = f2bf(fmaf(acc0, inv, bf2f(sr.x)));
    o.y = f2bf(fmaf(acc1, inv, bf2f(sr.y)));
    *(ushort2*)sx = o;
}

// ---------------- GEMM2 (MFMA) + epilogue ------------------------------------
// gate = sigmoid(nodes@Wg1 + x@Wg2); fuse = tanh(x@Wf); out = g*f + (1-g)*nodes
__global__ __launch_bounds__(256) void k_out(
    const float* __restrict__ nodes, const unsigned short* __restrict__ qkvs,
    const unsigned short* __restrict__ Wg1t, const unsigned short* __restrict__ Wg2t,
    const unsigned short* __restrict__ Wft, float* __restrict__ out)
{
    const int wave = threadIdx.x >> 6, lane = threadIdx.x & 63;
    const int row0 = (blockIdx.x * 4 + wave) * 32;
    if (row0 >= NN) return;
    const int arow  = row0 + (lane & 31);
    const int khalf = lane >> 5;

    f32x16 gacc[4], facc[4];
    #pragma unroll
    for (int cf = 0; cf < 4; ++cf)
        #pragma unroll
        for (int r = 0; r < 16; ++r) { gacc[cf][r] = 0.f; facc[cf][r] = 0.f; }

    #pragma unroll 1
    for (int ks = 0; ks < 8; ++ks) {
        const float* ap = nodes + (size_t)arow * FF + ks * 16 + khalf * 8;
        bf16x8 an = pack8(ap);
        bf16x8 ax = *(const bf16x8*)(qkvs + (size_t)arow * NQ + 384 + ks * 16 + khalf * 8);
        #pragma unroll
        for (int cf = 0; cf < 4; ++cf) {
            const int col = cf * 32 + (lane & 31);
            const size_t wo = (size_t)col * FF + ks * 16 + khalf * 8;
            gacc[cf] = __builtin_amdgcn_mfma_f32_32x32x16_bf16(an, *(const bf16x8*)(Wg1t + wo), gacc[cf], 0, 0, 0);
            gacc[cf] = __builtin_amdgcn_mfma_f32_32x32x16_bf16(ax, *(const bf16x8*)(Wg2t + wo), gacc[cf], 0, 0, 0);
            facc[cf] = __builtin_amdgcn_mfma_f32_32x32x16_bf16(ax, *(const bf16x8*)(Wft  + wo), facc[cf], 0, 0, 0);
        }
    }
    #pragma unroll
    for (int cf = 0; cf < 4; ++cf) {
        const int col = cf * 32 + (lane & 31);
        #pragma unroll
        for (int r = 0; r < 16; ++r) {
            const int rr = row0 + (r & 3) + 8 * (r >> 2) + 4 * (lane >> 5);
            const float g  = 1.0f / (1.0f + __expf(-gacc[cf][r]));
            const float e2 = __expf(2.0f * facc[cf][r]);
            const float fv = (e2 - 1.0f) / (e2 + 1.0f);     // tanh
            const float nv = nodes[(size_t)rr * FF + col];
            out[(size_t)rr * FF + col] = g * fv + (1.0f - g) * nv;
        }
    }
}

extern "C" void kernel_launch(void* const* d_in, const int* in_sizes, int n_in,
                              void* d_out, int out_size, void* d_ws, size_t ws_size,
                              hipStream_t stream) {
    const float* nodes = (const float*)d_in[0];
    const int*   ei    = (const int*)d_in[1];
    const int*   esrc  = ei;        // edge_index[0]
    const int*   edst  = ei + EE;   // edge_index[1]
    const float* Wq = (const float*)d_in[2];
    const float* bq = (const float*)d_in[3];
    const float* Wk = (const float*)d_in[4];
    const float* bk = (const float*)d_in[5];
    const float* Wv = (const float*)d_in[6];
    const float* bv = (const float*)d_in[7];
    const float* Ws = (const float*)d_in[8];
    const float* bs = (const float*)d_in[9];
    const float* Wg = (const float*)d_in[10];
    const float* Wf = (const float*)d_in[11];
    float* out = (float*)d_out;

    // ws layout (bytes):
    //   qkvs   : NN*512*2 = 102.4MB  (q|k|v|skip interleaved, bf16)
    //   Wt     : 512*128*2 = 131072
    //   Wg1t/Wg2t/Wft : 3 * 128*128*2 = 98304
    //   bias   : 512*4 = 2048
    //   count  : NN*4 = 400000
    //   srclist: NN*CAP*4 = 24MB
    char* wsb = (char*)d_ws;
    unsigned short* qkvs = (unsigned short*)wsb;
    unsigned short* Wt   = (unsigned short*)(wsb + (size_t)NN * NQ * 2);
    unsigned short* Wg1t = Wt + 512 * FF;
    unsigned short* Wg2t = Wg1t + FF * FF;
    unsigned short* Wft  = Wg2t + FF * FF;
    float* bias  = (float*)(Wft + FF * FF);
    int* count   = (int*)(bias + NQ);
    int* srclist = count + NN;

    hipMemsetAsync(count, 0, NN * sizeof(int), stream);

    k_prep<<<450, 256, 0, stream>>>(Wq, Wk, Wv, Ws, Wg, Wf, bq, bk, bv, bs,
                                    Wt, Wg1t, Wg2t, Wft, bias);
    k_build<<<(EE + 255) / 256, 256, 0, stream>>>(esrc, edst, count, srclist);
    k_qkvs<<<(NN + 127) / 128, 256, 0, stream>>>(nodes, Wt, bias, qkvs);
    k_attn<<<(NN * 64) / 256, 256, 0, stream>>>(qkvs, count, srclist);
    k_out<<<(NN + 127) / 128, 256, 0, stream>>>(nodes, qkvs, Wg1t, Wg2t, Wft, out);
}

// Round 3
// 493.744 us; speedup vs baseline: 1.4987x; 1.0707x over previous
//
#include <hip/hip_runtime.h>
#include <stdint.h>

#define NN 100000
#define EE 1600000
#define FF 128
#define CAP 60   // max tracked in-degree; Poisson(16) => P(deg>=60) ~ 1e-14

typedef __attribute__((ext_vector_type(8)))  short bf16x8;
typedef __attribute__((ext_vector_type(16))) float f32x16;

__device__ __forceinline__ float bf2f(unsigned short u) {
    union { unsigned int i; float f; } c; c.i = ((unsigned int)u) << 16; return c.f;
}
__device__ __forceinline__ unsigned short f2bf(float f) {
    union { unsigned int i; float f; } c; c.f = f;
    unsigned int u = c.i;
    return (unsigned short)((u + 0x7FFFu + ((u >> 16) & 1u)) >> 16);
}
__device__ __forceinline__ bf16x8 pack8(const float* p) {
    float4 f0 = *(const float4*)p;
    float4 f1 = *(const float4*)(p + 4);
    bf16x8 r;
    r[0] = (short)f2bf(f0.x); r[1] = (short)f2bf(f0.y);
    r[2] = (short)f2bf(f0.z); r[3] = (short)f2bf(f0.w);
    r[4] = (short)f2bf(f1.x); r[5] = (short)f2bf(f1.y);
    r[6] = (short)f2bf(f1.z); r[7] = (short)f2bf(f1.w);
    return r;
}

// ---------------- prep: transpose weights to [col][k] bf16, concat biases ---
__global__ __launch_bounds__(256) void k_prep(
    const float* __restrict__ Wq, const float* __restrict__ Wk,
    const float* __restrict__ Wv, const float* __restrict__ Ws,
    const float* __restrict__ Wg, const float* __restrict__ Wf,
    const float* __restrict__ bq, const float* __restrict__ bk,
    const float* __restrict__ bv, const float* __restrict__ bs,
    unsigned short* __restrict__ Wt, unsigned short* __restrict__ Wg1t,
    unsigned short* __restrict__ Wg2t, unsigned short* __restrict__ Wft,
    float* __restrict__ bias)
{
    int idx = blockIdx.x * 256 + threadIdx.x;
    if (idx < 65536) {
        int col = idx >> 7, k = idx & 127;
        int seg = col >> 7, c = col & 127;
        const float* W = (seg == 0) ? Wq : (seg == 1) ? Wk : (seg == 2) ? Wv : Ws;
        Wt[idx] = f2bf(W[k * FF + c]);
    } else if (idx < 81920) {
        int j = idx - 65536; int col = j >> 7, k = j & 127;
        Wg1t[j] = f2bf(Wg[k * FF + col]);
    } else if (idx < 98304) {
        int j = idx - 81920; int col = j >> 7, k = j & 127;
        Wg2t[j] = f2bf(Wg[(FF + k) * FF + col]);
    } else if (idx < 114688) {
        int j = idx - 98304; int col = j >> 7, k = j & 127;
        Wft[j] = f2bf(Wf[k * FF + col]);
    } else if (idx < 115200) {
        int j = idx - 114688;
        float b = (j < 128) ? bq[j] : (j < 256) ? bk[j - 128]
                : (j < 384) ? bv[j - 256] : bs[j - 384];
        bias[j] = b;
    }
}

// ---------------- GEMM1 (MFMA): [q|k|v|skip] = nodes @ W + b ----------------
// wave = 32 rows x 512 cols. Outputs split: q[N][128], kv[N][256], sx[N][128].
__global__ __launch_bounds__(256) void k_qkvs(
    const float* __restrict__ nodes, const unsigned short* __restrict__ Wt,
    const float* __restrict__ bias, unsigned short* __restrict__ qb,
    unsigned short* __restrict__ kvb, unsigned short* __restrict__ sxb)
{
    const int wave = threadIdx.x >> 6, lane = threadIdx.x & 63;
    const int row0 = (blockIdx.x * 4 + wave) * 32;
    if (row0 >= NN) return;
    const int arow  = row0 + (lane & 31);
    const int khalf = lane >> 5;                 // 0/1 -> k offset 0/8

    bf16x8 afr[8];                               // K=128 in 8 steps of 16
    const float* ap = nodes + (size_t)arow * FF + khalf * 8;
    #pragma unroll
    for (int ks = 0; ks < 8; ++ks) afr[ks] = pack8(ap + ks * 16);

    #pragma unroll 1
    for (int cg = 0; cg < 4; ++cg) {
        f32x16 acc[4];
        #pragma unroll
        for (int cf = 0; cf < 4; ++cf)
            #pragma unroll
            for (int r = 0; r < 16; ++r) acc[cf][r] = 0.f;

        #pragma unroll
        for (int ks = 0; ks < 8; ++ks) {
            #pragma unroll
            for (int cf = 0; cf < 4; ++cf) {
                const int col = cg * 128 + cf * 32 + (lane & 31);
                bf16x8 b = *(const bf16x8*)(Wt + (size_t)col * FF + ks * 16 + khalf * 8);
                acc[cf] = __builtin_amdgcn_mfma_f32_32x32x16_bf16(afr[ks], b, acc[cf], 0, 0, 0);
            }
        }
        #pragma unroll
        for (int cf = 0; cf < 4; ++cf) {
            const int col = cf * 32 + (lane & 31);          // 0..127 within segment
            const float bv = bias[cg * 128 + col];
            #pragma unroll
            for (int r = 0; r < 16; ++r) {
                const int rr = row0 + (r & 3) + 8 * (r >> 2) + 4 * (lane >> 5);
                unsigned short val = f2bf(acc[cf][r] + bv);
                if (cg == 0)      qb [(size_t)rr * 128 + col]       = val;
                else if (cg == 1) kvb[(size_t)rr * 256 + col]       = val;
                else if (cg == 2) kvb[(size_t)rr * 256 + 128 + col] = val;
                else              sxb[(size_t)rr * 128 + col]       = val;
            }
        }
    }
}

// ---------------- build per-dst bucket lists ---------------------------------
__global__ __launch_bounds__(256) void k_build(
    const int* __restrict__ src, const int* __restrict__ dst,
    int* __restrict__ count, int* __restrict__ srclist)
{
    int e = blockIdx.x * 256 + threadIdx.x;
    if (e >= EE) return;
    int d = dst[e];
    int s = src[e];
    int r = atomicAdd(&count[d], 1);
    if (r < CAP) srclist[(size_t)d * CAP + r] = s;
}

// ---------------- per-destination attention (1 wave per node) ----------------
// Lane groups of 16: group g = lane>>4 -> (edge-stream = g>>1, head = g&1).
// Each lane holds 4 dims: head*64 + (lane&15)*4 .. +3. Two edges per iteration.
__global__ __launch_bounds__(256) void k_attn(
    const unsigned short* __restrict__ qb, const unsigned short* __restrict__ kvb,
    unsigned short* __restrict__ sxb,
    const int* __restrict__ count, const int* __restrict__ srclist)
{
    const int wid = (int)((blockIdx.x * 256 + threadIdx.x) >> 6);
    if (wid >= NN) return;
    const int lane = threadIdx.x & 63;
    const int half = lane >> 5;           // edge stream 0/1
    const int lh   = lane & 31;
    const int hd64 = (lh >> 4) * 64;      // head offset
    const int t4   = (lh & 15) * 4;       // dim-quad within head

    const ushort4 qr = *(const ushort4*)(qb + (size_t)wid * FF + hd64 + t4);
    const float qa0 = bf2f(qr.x), qa1 = bf2f(qr.y), qa2 = bf2f(qr.z), qa3 = bf2f(qr.w);

    int deg = __builtin_amdgcn_readfirstlane(count[wid]);
    if (deg > CAP) deg = CAP;
    const size_t base = (size_t)wid * CAP;
    const int sreg = srclist[base + (lane < CAP ? lane : CAP - 1)];

    float denom = 0.f, acc0 = 0.f, acc1 = 0.f, acc2 = 0.f, acc3 = 0.f;
    const int nit = (deg + 1) >> 1;
    #pragma unroll 2
    for (int it = 0; it < nit; ++it) {
        const int idx  = 2 * it + half;
        const int sidx = idx < deg ? idx : deg - 1;
        const int s    = __shfl(sreg, sidx);
        const ushort4 kr = *(const ushort4*)(kvb + (size_t)s * 256 + hd64 + t4);
        const ushort4 vr = *(const ushort4*)(kvb + (size_t)s * 256 + 128 + hd64 + t4);
        float p = qa0 * bf2f(kr.x) + qa1 * bf2f(kr.y) + qa2 * bf2f(kr.z) + qa3 * bf2f(kr.w);
        p += __shfl_xor(p, 1);
        p += __shfl_xor(p, 2);
        p += __shfl_xor(p, 4);
        p += __shfl_xor(p, 8);            // 16-lane group sum = per-head logit
        const float ex = (idx < deg) ? __expf(p * 0.125f) : 0.f;
        denom += ex;
        acc0 = fmaf(ex, bf2f(vr.x), acc0);
        acc1 = fmaf(ex, bf2f(vr.y), acc1);
        acc2 = fmaf(ex, bf2f(vr.z), acc2);
        acc3 = fmaf(ex, bf2f(vr.w), acc3);
    }
    // fold the two edge streams (lane <-> lane^32)
    denom += __shfl_xor(denom, 32);
    acc0  += __shfl_xor(acc0, 32);
    acc1  += __shfl_xor(acc1, 32);
    acc2  += __shfl_xor(acc2, 32);
    acc3  += __shfl_xor(acc3, 32);

    if (half == 0) {
        const float inv = (denom > 0.f) ? (1.0f / denom) : 0.f;
        unsigned short* sx = sxb + (size_t)wid * FF + hd64 + t4;
        const ushort4 sr = *(const ushort4*)sx;
        ushort4 o;
        o.x = f2bf(fmaf(acc0, inv, bf2f(sr.x)));
        o.y = f2bf(fmaf(acc1, inv, bf2f(sr.y)));
        o.z = f2bf(fmaf(acc2, inv, bf2f(sr.z)));
        o.w = f2bf(fmaf(acc3, inv, bf2f(sr.w)));
        *(ushort4*)sx = o;
    }
}

// ---------------- GEMM2 (MFMA) + epilogue ------------------------------------
__global__ __launch_bounds__(256) void k_out(
    const float* __restrict__ nodes, const unsigned short* __restrict__ sxb,
    const unsigned short* __restrict__ Wg1t, const unsigned short* __restrict__ Wg2t,
    const unsigned short* __restrict__ Wft, float* __restrict__ out)
{
    const int wave = threadIdx.x >> 6, lane = threadIdx.x & 63;
    const int row0 = (blockIdx.x * 4 + wave) * 32;
    if (row0 >= NN) return;
    const int arow  = row0 + (lane & 31);
    const int khalf = lane >> 5;

    f32x16 gacc[4], facc[4];
    #pragma unroll
    for (int cf = 0; cf < 4; ++cf)
        #pragma unroll
        for (int r = 0; r < 16; ++r) { gacc[cf][r] = 0.f; facc[cf][r] = 0.f; }

    #pragma unroll 1
    for (int ks = 0; ks < 8; ++ks) {
        const float* ap = nodes + (size_t)arow * FF + ks * 16 + khalf * 8;
        bf16x8 an = pack8(ap);
        bf16x8 ax = *(const bf16x8*)(sxb + (size_t)arow * FF + ks * 16 + khalf * 8);
        #pragma unroll
        for (int cf = 0; cf < 4; ++cf) {
            const int col = cf * 32 + (lane & 31);
            const size_t wo = (size_t)col * FF + ks * 16 + khalf * 8;
            gacc[cf] = __builtin_amdgcn_mfma_f32_32x32x16_bf16(an, *(const bf16x8*)(Wg1t + wo), gacc[cf], 0, 0, 0);
            gacc[cf] = __builtin_amdgcn_mfma_f32_32x32x16_bf16(ax, *(const bf16x8*)(Wg2t + wo), gacc[cf], 0, 0, 0);
            facc[cf] = __builtin_amdgcn_mfma_f32_32x32x16_bf16(ax, *(const bf16x8*)(Wft  + wo), facc[cf], 0, 0, 0);
        }
    }
    #pragma unroll
    for (int cf = 0; cf < 4; ++cf) {
        const int col = cf * 32 + (lane & 31);
        #pragma unroll
        for (int r = 0; r < 16; ++r) {
            const int rr = row0 + (r & 3) + 8 * (r >> 2) + 4 * (lane >> 5);
            const float g  = 1.0f / (1.0f + __expf(-gacc[cf][r]));
            const float e2 = __expf(2.0f * facc[cf][r]);
            const float fv = (e2 - 1.0f) / (e2 + 1.0f);     // tanh
            const float nv = nodes[(size_t)rr * FF + col];
            out[(size_t)rr * FF + col] = g * fv + (1.0f - g) * nv;
        }
    }
}

extern "C" void kernel_launch(void* const* d_in, const int* in_sizes, int n_in,
                              void* d_out, int out_size, void* d_ws, size_t ws_size,
                              hipStream_t stream) {
    const float* nodes = (const float*)d_in[0];
    const int*   ei    = (const int*)d_in[1];
    const int*   esrc  = ei;        // edge_index[0]
    const int*   edst  = ei + EE;   // edge_index[1]
    const float* Wq = (const float*)d_in[2];
    const float* bq = (const float*)d_in[3];
    const float* Wk = (const float*)d_in[4];
    const float* bk = (const float*)d_in[5];
    const float* Wv = (const float*)d_in[6];
    const float* bv = (const float*)d_in[7];
    const float* Ws = (const float*)d_in[8];
    const float* bs = (const float*)d_in[9];
    const float* Wg = (const float*)d_in[10];
    const float* Wf = (const float*)d_in[11];
    float* out = (float*)d_out;

    // ws layout:
    //   qb  : NN*128*2 = 25.6MB
    //   kvb : NN*256*2 = 51.2MB   (k|v per node, gather target)
    //   sxb : NN*128*2 = 25.6MB   (skip -> x)
    //   Wt / Wg1t / Wg2t / Wft / bias : ~0.25MB
    //   count: 0.4MB; srclist: NN*CAP*4 = 24MB
    char* wsb = (char*)d_ws;
    unsigned short* qb   = (unsigned short*)wsb;
    unsigned short* kvb  = qb + (size_t)NN * 128;
    unsigned short* sxb  = kvb + (size_t)NN * 256;
    unsigned short* Wt   = sxb + (size_t)NN * 128;
    unsigned short* Wg1t = Wt + 512 * FF;
    unsigned short* Wg2t = Wg1t + FF * FF;
    unsigned short* Wft  = Wg2t + FF * FF;
    float* bias  = (float*)(Wft + FF * FF);
    int* count   = (int*)(bias + 512);
    int* srclist = count + NN;

    hipMemsetAsync(count, 0, NN * sizeof(int), stream);

    k_prep<<<450, 256, 0, stream>>>(Wq, Wk, Wv, Ws, Wg, Wf, bq, bk, bv, bs,
                                    Wt, Wg1t, Wg2t, Wft, bias);
    k_build<<<(EE + 255) / 256, 256, 0, stream>>>(esrc, edst, count, srclist);
    k_qkvs<<<(NN + 127) / 128, 256, 0, stream>>>(nodes, Wt, bias, qb, kvb, sxb);
    k_attn<<<(NN * 64) / 256, 256, 0, stream>>>(qb, kvb, sxb, count, srclist);
    k_out<<<(NN + 127) / 128, 256, 0, stream>>>(nodes, sxb, Wg1t, Wg2t, Wft, out);
}

// Round 4
// 388.095 us; speedup vs baseline: 1.9067x; 1.2722x over previous
//
#include <hip/hip_runtime.h>
#include <stdint.h>

#define NN 100000
#define EE 1600000
#define FF 128
#define CAP 60   // max tracked in-degree; Poisson(16) => P(deg>=60) ~ 1e-14

typedef __attribute__((ext_vector_type(8)))  short bf16x8;
typedef __attribute__((ext_vector_type(16))) float f32x16;

__device__ __forceinline__ float bf2f(unsigned short u) {
    union { unsigned int i; float f; } c; c.i = ((unsigned int)u) << 16; return c.f;
}
__device__ __forceinline__ unsigned short f2bf(float f) {
    union { unsigned int i; float f; } c; c.f = f;
    unsigned int u = c.i;
    return (unsigned short)((u + 0x7FFFu + ((u >> 16) & 1u)) >> 16);
}
__device__ __forceinline__ bf16x8 pack8(const float* p) {
    float4 f0 = *(const float4*)p;
    float4 f1 = *(const float4*)(p + 4);
    bf16x8 r;
    r[0] = (short)f2bf(f0.x); r[1] = (short)f2bf(f0.y);
    r[2] = (short)f2bf(f0.z); r[3] = (short)f2bf(f0.w);
    r[4] = (short)f2bf(f1.x); r[5] = (short)f2bf(f1.y);
    r[6] = (short)f2bf(f1.z); r[7] = (short)f2bf(f1.w);
    return r;
}

// ---------------- prep: pack weights into MFMA B-fragment order --------------
// Wp : 4cg x 4cf x 8ks x 64lane x 8  (qkvs weights, fragment-linear)
// Wp2: 3mat x 4cf x 8ks x 64lane x 8 (gate1, gate2, fuse)
// B-frag for mfma_32x32x16_bf16: lane holds B[k=ks*16+(lane>>5)*8+j][col=base+(lane&31)]
__global__ __launch_bounds__(256) void k_prep(
    const float* __restrict__ Wq, const float* __restrict__ Wk,
    const float* __restrict__ Wv, const float* __restrict__ Ws,
    const float* __restrict__ Wg, const float* __restrict__ Wf,
    const float* __restrict__ bq, const float* __restrict__ bk,
    const float* __restrict__ bv, const float* __restrict__ bs,
    unsigned short* __restrict__ Wp, unsigned short* __restrict__ Wp2,
    float* __restrict__ bias)
{
    int idx = blockIdx.x * 256 + threadIdx.x;
    if (idx < 65536) {
        int j = idx & 7, lane = (idx >> 3) & 63, ks = (idx >> 9) & 7;
        int cf = (idx >> 12) & 3, cg = idx >> 14;
        int c  = cf * 32 + (lane & 31);
        int kk = ks * 16 + (lane >> 5) * 8 + j;
        const float* W = (cg == 0) ? Wq : (cg == 1) ? Wk : (cg == 2) ? Wv : Ws;
        Wp[idx] = f2bf(W[kk * FF + c]);
    } else if (idx < 65536 + 49152) {
        int p = idx - 65536;
        int j = p & 7, lane = (p >> 3) & 63, ks = (p >> 9) & 7;
        int cf = (p >> 12) & 3, mat = p >> 14;
        int c  = cf * 32 + (lane & 31);
        int kk = ks * 16 + (lane >> 5) * 8 + j;
        float v = (mat == 0) ? Wg[kk * FF + c]
                : (mat == 1) ? Wg[(FF + kk) * FF + c]
                             : Wf[kk * FF + c];
        Wp2[p] = f2bf(v);
    } else if (idx < 65536 + 49152 + 512) {
        int j = idx - (65536 + 49152);
        float b = (j < 128) ? bq[j] : (j < 256) ? bk[j - 128]
                : (j < 384) ? bv[j - 256] : bs[j - 384];
        bias[j] = b;
    }
}

// ---------------- nodes -> bf16 (coalesced) ----------------------------------
__global__ __launch_bounds__(256) void k_nb(
    const float* __restrict__ nodes, unsigned short* __restrict__ nb)
{
    size_t i = ((size_t)blockIdx.x * 256 + threadIdx.x) * 8;   // 12.8M elems
    *(bf16x8*)(nb + i) = pack8(nodes + i);
}

// ---------------- GEMM1 (MFMA): [q|k|v|skip] = nb @ W + b --------------------
// block = 32 rows; wave w computes col-group cg=w (128 cols). B coalesced from Wp.
__global__ __launch_bounds__(256) void k_qkvs(
    const unsigned short* __restrict__ nb, const unsigned short* __restrict__ Wp,
    const float* __restrict__ bias, unsigned short* __restrict__ qb,
    unsigned short* __restrict__ kvb, unsigned short* __restrict__ sxb)
{
    const int wave = threadIdx.x >> 6, lane = threadIdx.x & 63;
    const int row0 = blockIdx.x * 32;
    const int arow = row0 + (lane & 31);
    const int khalf = lane >> 5;
    const int cg = wave;

    bf16x8 afr[8];
    const unsigned short* ap = nb + (size_t)arow * FF + khalf * 8;
    #pragma unroll
    for (int ks = 0; ks < 8; ++ks) afr[ks] = *(const bf16x8*)(ap + ks * 16);

    f32x16 acc[4];
    #pragma unroll
    for (int cf = 0; cf < 4; ++cf)
        #pragma unroll
        for (int r = 0; r < 16; ++r) acc[cf][r] = 0.f;

    #pragma unroll
    for (int ks = 0; ks < 8; ++ks) {
        #pragma unroll
        for (int cf = 0; cf < 4; ++cf) {
            bf16x8 b = *(const bf16x8*)(Wp + (((cg * 4 + cf) * 8 + ks) << 9) + (lane << 3));
            acc[cf] = __builtin_amdgcn_mfma_f32_32x32x16_bf16(afr[ks], b, acc[cf], 0, 0, 0);
        }
    }

    #pragma unroll
    for (int cf = 0; cf < 4; ++cf) {
        const int col = cf * 32 + (lane & 31);
        const float bv = bias[cg * 128 + col];
        #pragma unroll
        for (int r = 0; r < 16; ++r) {
            const int rr = row0 + (r & 3) + 8 * (r >> 2) + 4 * (lane >> 5);
            unsigned short val = f2bf(acc[cf][r] + bv);
            if (cg == 0)      qb [(size_t)rr * 128 + col]       = val;
            else if (cg == 1) kvb[(size_t)rr * 256 + col]       = val;
            else if (cg == 2) kvb[(size_t)rr * 256 + 128 + col] = val;
            else              sxb[(size_t)rr * 128 + col]       = val;
        }
    }
}

// ---------------- build per-dst bucket lists ---------------------------------
__global__ __launch_bounds__(256) void k_build(
    const int* __restrict__ src, const int* __restrict__ dst,
    int* __restrict__ count, int* __restrict__ srclist)
{
    int e = blockIdx.x * 256 + threadIdx.x;
    if (e >= EE) return;
    int d = dst[e];
    int s = src[e];
    int r = atomicAdd(&count[d], 1);
    if (r < CAP) srclist[(size_t)d * CAP + r] = s;
}

// ---------------- per-destination attention (1 wave per node) ----------------
// Lane groups of 16: group g = lane>>4 -> (edge-stream = g>>1, head = g&1).
// Each lane holds 4 dims. Two edges per iteration.
__global__ __launch_bounds__(256) void k_attn(
    const unsigned short* __restrict__ qb, const unsigned short* __restrict__ kvb,
    unsigned short* __restrict__ sxb,
    const int* __restrict__ count, const int* __restrict__ srclist)
{
    const int wid = (int)((blockIdx.x * 256 + threadIdx.x) >> 6);
    if (wid >= NN) return;
    const int lane = threadIdx.x & 63;
    const int half = lane >> 5;           // edge stream 0/1
    const int lh   = lane & 31;
    const int hd64 = (lh >> 4) * 64;      // head offset
    const int t4   = (lh & 15) * 4;       // dim-quad within head

    const ushort4 qr = *(const ushort4*)(qb + (size_t)wid * FF + hd64 + t4);
    const float qa0 = bf2f(qr.x), qa1 = bf2f(qr.y), qa2 = bf2f(qr.z), qa3 = bf2f(qr.w);

    int deg = __builtin_amdgcn_readfirstlane(count[wid]);
    if (deg > CAP) deg = CAP;
    const size_t base = (size_t)wid * CAP;
    const int sreg = srclist[base + (lane < CAP ? lane : CAP - 1)];

    float denom = 0.f, acc0 = 0.f, acc1 = 0.f, acc2 = 0.f, acc3 = 0.f;
    const int nit = (deg + 1) >> 1;
    #pragma unroll 2
    for (int it = 0; it < nit; ++it) {
        const int idx  = 2 * it + half;
        const int sidx = idx < deg ? idx : deg - 1;
        const int s    = __shfl(sreg, sidx);
        const ushort4 kr = *(const ushort4*)(kvb + (size_t)s * 256 + hd64 + t4);
        const ushort4 vr = *(const ushort4*)(kvb + (size_t)s * 256 + 128 + hd64 + t4);
        float p = qa0 * bf2f(kr.x) + qa1 * bf2f(kr.y) + qa2 * bf2f(kr.z) + qa3 * bf2f(kr.w);
        p += __shfl_xor(p, 1);
        p += __shfl_xor(p, 2);
        p += __shfl_xor(p, 4);
        p += __shfl_xor(p, 8);            // 16-lane group sum = per-head logit
        const float ex = (idx < deg) ? __expf(p * 0.125f) : 0.f;
        denom += ex;
        acc0 = fmaf(ex, bf2f(vr.x), acc0);
        acc1 = fmaf(ex, bf2f(vr.y), acc1);
        acc2 = fmaf(ex, bf2f(vr.z), acc2);
        acc3 = fmaf(ex, bf2f(vr.w), acc3);
    }
    denom += __shfl_xor(denom, 32);
    acc0  += __shfl_xor(acc0, 32);
    acc1  += __shfl_xor(acc1, 32);
    acc2  += __shfl_xor(acc2, 32);
    acc3  += __shfl_xor(acc3, 32);

    if (half == 0) {
        const float inv = (denom > 0.f) ? (1.0f / denom) : 0.f;
        unsigned short* sx = sxb + (size_t)wid * FF + hd64 + t4;
        const ushort4 sr = *(const ushort4*)sx;
        ushort4 o;
        o.x = f2bf(fmaf(acc0, inv, bf2f(sr.x)));
        o.y = f2bf(fmaf(acc1, inv, bf2f(sr.y)));
        o.z = f2bf(fmaf(acc2, inv, bf2f(sr.z)));
        o.w = f2bf(fmaf(acc3, inv, bf2f(sr.w)));
        *(ushort4*)sx = o;
    }
}

// ---------------- GEMM2 (MFMA) + epilogue ------------------------------------
// block = 32 rows; wave w computes cols w*32..w*32+31 (3 MFMA chains).
__global__ __launch_bounds__(256) void k_out(
    const unsigned short* __restrict__ nb, const unsigned short* __restrict__ sxb,
    const unsigned short* __restrict__ Wp2, float* __restrict__ out)
{
    const int wave = threadIdx.x >> 6, lane = threadIdx.x & 63;
    const int row0 = blockIdx.x * 32;
    const int arow = row0 + (lane & 31);
    const int khalf = lane >> 5;
    const int cf = wave;

    f32x16 gacc, facc;
    #pragma unroll
    for (int r = 0; r < 16; ++r) { gacc[r] = 0.f; facc[r] = 0.f; }

    #pragma unroll
    for (int ks = 0; ks < 8; ++ks) {
        bf16x8 an = *(const bf16x8*)(nb  + (size_t)arow * FF + ks * 16 + khalf * 8);
        bf16x8 ax = *(const bf16x8*)(sxb + (size_t)arow * FF + ks * 16 + khalf * 8);
        bf16x8 b0 = *(const bf16x8*)(Wp2 + (((0 * 4 + cf) * 8 + ks) << 9) + (lane << 3));
        bf16x8 b1 = *(const bf16x8*)(Wp2 + (((1 * 4 + cf) * 8 + ks) << 9) + (lane << 3));
        bf16x8 b2 = *(const bf16x8*)(Wp2 + (((2 * 4 + cf) * 8 + ks) << 9) + (lane << 3));
        gacc = __builtin_amdgcn_mfma_f32_32x32x16_bf16(an, b0, gacc, 0, 0, 0);
        gacc = __builtin_amdgcn_mfma_f32_32x32x16_bf16(ax, b1, gacc, 0, 0, 0);
        facc = __builtin_amdgcn_mfma_f32_32x32x16_bf16(ax, b2, facc, 0, 0, 0);
    }

    const int col = cf * 32 + (lane & 31);
    #pragma unroll
    for (int r = 0; r < 16; ++r) {
        const int rr = row0 + (r & 3) + 8 * (r >> 2) + 4 * (lane >> 5);
        const float g  = 1.0f / (1.0f + __expf(-gacc[r]));
        const float e2 = __expf(2.0f * facc[r]);
        const float fv = (e2 - 1.0f) / (e2 + 1.0f);     // tanh
        const float nv = bf2f(nb[(size_t)rr * FF + col]);
        out[(size_t)rr * FF + col] = g * fv + (1.0f - g) * nv;
    }
}

extern "C" void kernel_launch(void* const* d_in, const int* in_sizes, int n_in,
                              void* d_out, int out_size, void* d_ws, size_t ws_size,
                              hipStream_t stream) {
    const float* nodes = (const float*)d_in[0];
    const int*   ei    = (const int*)d_in[1];
    const int*   esrc  = ei;        // edge_index[0]
    const int*   edst  = ei + EE;   // edge_index[1]
    const float* Wq = (const float*)d_in[2];
    const float* bq = (const float*)d_in[3];
    const float* Wk = (const float*)d_in[4];
    const float* bk = (const float*)d_in[5];
    const float* Wv = (const float*)d_in[6];
    const float* bv = (const float*)d_in[7];
    const float* Ws = (const float*)d_in[8];
    const float* bs = (const float*)d_in[9];
    const float* Wg = (const float*)d_in[10];
    const float* Wf = (const float*)d_in[11];
    float* out = (float*)d_out;

    // ws layout:
    //   qb  : NN*128*2 = 25.6MB
    //   kvb : NN*256*2 = 51.2MB   (k|v per node, gather target)
    //   sxb : NN*128*2 = 25.6MB   (skip -> x)
    //   nb  : NN*128*2 = 25.6MB   (nodes bf16)
    //   Wp  : 65536*2; Wp2 : 49152*2; bias : 512*4
    //   count: 0.4MB; srclist: NN*CAP*4 = 24MB        total ~153MB
    char* wsb = (char*)d_ws;
    unsigned short* qb   = (unsigned short*)wsb;
    unsigned short* kvb  = qb + (size_t)NN * 128;
    unsigned short* sxb  = kvb + (size_t)NN * 256;
    unsigned short* nb   = sxb + (size_t)NN * 128;
    unsigned short* Wp   = nb + (size_t)NN * 128;
    unsigned short* Wp2  = Wp + 65536;
    float* bias  = (float*)(Wp2 + 49152);
    int* count   = (int*)(bias + 512);
    int* srclist = count + NN;

    hipMemsetAsync(count, 0, NN * sizeof(int), stream);

    k_prep<<<450, 256, 0, stream>>>(Wq, Wk, Wv, Ws, Wg, Wf, bq, bk, bv, bs,
                                    Wp, Wp2, bias);
    k_nb<<<(NN * FF / 8 + 255) / 256, 256, 0, stream>>>(nodes, nb);
    k_build<<<(EE + 255) / 256, 256, 0, stream>>>(esrc, edst, count, srclist);
    k_qkvs<<<NN / 32, 256, 0, stream>>>(nb, Wp, bias, qb, kvb, sxb);
    k_attn<<<(NN * 64) / 256, 256, 0, stream>>>(qb, kvb, sxb, count, srclist);
    k_out<<<NN / 32, 256, 0, stream>>>(nb, sxb, Wp2, out);
}

// Round 5
// 373.783 us; speedup vs baseline: 1.9797x; 1.0383x over previous
//
#include <hip/hip_runtime.h>
#include <stdint.h>

#define NN 100000
#define EE 1600000
#define FF 128
#define CAP 60   // max tracked in-degree; Poisson(16) => P(deg>=60) ~ 1e-14

typedef __attribute__((ext_vector_type(8)))  short bf16x8;
typedef __attribute__((ext_vector_type(8)))  unsigned short u16x8;
typedef __attribute__((ext_vector_type(16))) float f32x16;

#define NB_BLOCKS   6250   // nodes->bf16: 12.8M elems / 8 / 256
#define BUILD_BLOCKS 6250  // 1.6M edges / 256
#define PREP_BLOCKS 450

__device__ __forceinline__ float bf2f(unsigned short u) {
    union { unsigned int i; float f; } c; c.i = ((unsigned int)u) << 16; return c.f;
}
__device__ __forceinline__ unsigned short f2bf(float f) {
    union { unsigned int i; float f; } c; c.f = f;
    unsigned int u = c.i;
    return (unsigned short)((u + 0x7FFFu + ((u >> 16) & 1u)) >> 16);
}
__device__ __forceinline__ bf16x8 pack8(const float* p) {
    float4 f0 = *(const float4*)p;
    float4 f1 = *(const float4*)(p + 4);
    bf16x8 r;
    r[0] = (short)f2bf(f0.x); r[1] = (short)f2bf(f0.y);
    r[2] = (short)f2bf(f0.z); r[3] = (short)f2bf(f0.w);
    r[4] = (short)f2bf(f1.x); r[5] = (short)f2bf(f1.y);
    r[6] = (short)f2bf(f1.z); r[7] = (short)f2bf(f1.w);
    return r;
}

// ---------------- F1: fused {build | prep | nodes->bf16} ---------------------
// All three are mutually independent. build is latency/transaction-bound with
// ~0.4% VALU, so prep/nb ride free on the idle machine.
__global__ __launch_bounds__(256) void k_f1(
    const int* __restrict__ src, const int* __restrict__ dst,
    int* __restrict__ count, int* __restrict__ srclist,
    const float* __restrict__ Wq, const float* __restrict__ Wk,
    const float* __restrict__ Wv, const float* __restrict__ Ws,
    const float* __restrict__ Wg, const float* __restrict__ Wf,
    const float* __restrict__ bq, const float* __restrict__ bk,
    const float* __restrict__ bv, const float* __restrict__ bs,
    unsigned short* __restrict__ Wp, unsigned short* __restrict__ Wp2,
    float* __restrict__ bias,
    const float* __restrict__ nodes, unsigned short* __restrict__ nb)
{
    const int bid = blockIdx.x;
    if (bid < BUILD_BLOCKS) {
        int e = bid * 256 + threadIdx.x;
        if (e >= EE) return;
        int d = dst[e];
        int s = src[e];
        int r = atomicAdd(&count[d], 1);
        if (r < CAP) srclist[(size_t)d * CAP + r] = s;
    } else if (bid < BUILD_BLOCKS + NB_BLOCKS) {
        size_t i = ((size_t)(bid - BUILD_BLOCKS) * 256 + threadIdx.x) * 8;
        *(bf16x8*)(nb + i) = pack8(nodes + i);
    } else {
        int idx = (bid - BUILD_BLOCKS - NB_BLOCKS) * 256 + threadIdx.x;
        if (idx < 65536) {
            int j = idx & 7, lane = (idx >> 3) & 63, ks = (idx >> 9) & 7;
            int cf = (idx >> 12) & 3, cg = idx >> 14;
            int c  = cf * 32 + (lane & 31);
            int kk = ks * 16 + (lane >> 5) * 8 + j;
            const float* W = (cg == 0) ? Wq : (cg == 1) ? Wk : (cg == 2) ? Wv : Ws;
            Wp[idx] = f2bf(W[kk * FF + c]);
        } else if (idx < 65536 + 49152) {
            int p = idx - 65536;
            int j = p & 7, lane = (p >> 3) & 63, ks = (p >> 9) & 7;
            int cf = (p >> 12) & 3, mat = p >> 14;
            int c  = cf * 32 + (lane & 31);
            int kk = ks * 16 + (lane >> 5) * 8 + j;
            float v = (mat == 0) ? Wg[kk * FF + c]
                    : (mat == 1) ? Wg[(FF + kk) * FF + c]
                                 : Wf[kk * FF + c];
            Wp2[p] = f2bf(v);
        } else if (idx < 65536 + 49152 + 512) {
            int j = idx - (65536 + 49152);
            float b = (j < 128) ? bq[j] : (j < 256) ? bk[j - 128]
                    : (j < 384) ? bv[j - 256] : bs[j - 384];
            bias[j] = b;
        }
    }
}

// ---------------- GEMM1 (MFMA): [q|k|v|skip] = nb @ W + b --------------------
// kvb layout (per node, 256 ushorts): chunk c (0..15) of 8 ushorts =
//   { k[4c..4c+3], v[4c..4c+3] }  -> one 16B lane-load serves both in attn.
__global__ __launch_bounds__(256) void k_qkvs(
    const unsigned short* __restrict__ nb, const unsigned short* __restrict__ Wp,
    const float* __restrict__ bias, unsigned short* __restrict__ qb,
    unsigned short* __restrict__ kvb, unsigned short* __restrict__ sxb)
{
    const int wave = threadIdx.x >> 6, lane = threadIdx.x & 63;
    const int row0 = blockIdx.x * 32;
    const int arow = row0 + (lane & 31);
    const int khalf = lane >> 5;
    const int cg = wave;

    bf16x8 afr[8];
    const unsigned short* ap = nb + (size_t)arow * FF + khalf * 8;
    #pragma unroll
    for (int ks = 0; ks < 8; ++ks) afr[ks] = *(const bf16x8*)(ap + ks * 16);

    f32x16 acc[4];
    #pragma unroll
    for (int cf = 0; cf < 4; ++cf)
        #pragma unroll
        for (int r = 0; r < 16; ++r) acc[cf][r] = 0.f;

    #pragma unroll
    for (int ks = 0; ks < 8; ++ks) {
        #pragma unroll
        for (int cf = 0; cf < 4; ++cf) {
            bf16x8 b = *(const bf16x8*)(Wp + (((cg * 4 + cf) * 8 + ks) << 9) + (lane << 3));
            acc[cf] = __builtin_amdgcn_mfma_f32_32x32x16_bf16(afr[ks], b, acc[cf], 0, 0, 0);
        }
    }

    #pragma unroll
    for (int cf = 0; cf < 4; ++cf) {
        const int col = cf * 32 + (lane & 31);
        const float bv = bias[cg * 128 + col];
        #pragma unroll
        for (int r = 0; r < 16; ++r) {
            const int rr = row0 + (r & 3) + 8 * (r >> 2) + 4 * (lane >> 5);
            unsigned short val = f2bf(acc[cf][r] + bv);
            if (cg == 0)      qb [(size_t)rr * 128 + col] = val;
            else if (cg == 1) kvb[(size_t)rr * 256 + (col >> 2) * 8 + (col & 3)]     = val;
            else if (cg == 2) kvb[(size_t)rr * 256 + (col >> 2) * 8 + 4 + (col & 3)] = val;
            else              sxb[(size_t)rr * 128 + col] = val;
        }
    }
}

// ---------------- per-destination attention (1 wave per node) ----------------
// Lane groups of 16: group g = lane>>4 -> (edge-stream = g>>1, head = g&1).
// Each lane: ONE 16B load per edge = {k quad, v quad} via interleaved kvb.
__global__ __launch_bounds__(256) void k_attn(
    const unsigned short* __restrict__ qb, const unsigned short* __restrict__ kvb,
    unsigned short* __restrict__ sxb,
    const int* __restrict__ count, const int* __restrict__ srclist)
{
    const int wid = (int)((blockIdx.x * 256 + threadIdx.x) >> 6);
    if (wid >= NN) return;
    const int lane = threadIdx.x & 63;
    const int half = lane >> 5;           // edge stream 0/1
    const int lh   = lane & 31;
    const int hd64 = (lh >> 4) * 64;      // head offset (q addressing)
    const int t4   = (lh & 15) * 4;       // dim-quad within head
    const int chunk = (hd64 + t4) >> 2;   // 16B chunk index in kvb row

    const ushort4 qr = *(const ushort4*)(qb + (size_t)wid * FF + hd64 + t4);
    const float qa0 = bf2f(qr.x), qa1 = bf2f(qr.y), qa2 = bf2f(qr.z), qa3 = bf2f(qr.w);

    int deg = __builtin_amdgcn_readfirstlane(count[wid]);
    if (deg > CAP) deg = CAP;
    const size_t base = (size_t)wid * CAP;
    const int sreg = srclist[base + (lane < CAP ? lane : CAP - 1)];

    float denom = 0.f, acc0 = 0.f, acc1 = 0.f, acc2 = 0.f, acc3 = 0.f;
    const int nit = (deg + 1) >> 1;
    #pragma unroll 2
    for (int it = 0; it < nit; ++it) {
        const int idx  = 2 * it + half;
        const int sidx = idx < deg ? idx : deg - 1;
        const int s    = __shfl(sreg, sidx);
        const u16x8 kv = *(const u16x8*)(kvb + (size_t)s * 256 + chunk * 8);
        float p = qa0 * bf2f(kv[0]) + qa1 * bf2f(kv[1]) + qa2 * bf2f(kv[2]) + qa3 * bf2f(kv[3]);
        p += __shfl_xor(p, 1);
        p += __shfl_xor(p, 2);
        p += __shfl_xor(p, 4);
        p += __shfl_xor(p, 8);            // 16-lane group sum = per-head logit
        const float ex = (idx < deg) ? __expf(p * 0.125f) : 0.f;
        denom += ex;
        acc0 = fmaf(ex, bf2f(kv[4]), acc0);
        acc1 = fmaf(ex, bf2f(kv[5]), acc1);
        acc2 = fmaf(ex, bf2f(kv[6]), acc2);
        acc3 = fmaf(ex, bf2f(kv[7]), acc3);
    }
    denom += __shfl_xor(denom, 32);
    acc0  += __shfl_xor(acc0, 32);
    acc1  += __shfl_xor(acc1, 32);
    acc2  += __shfl_xor(acc2, 32);
    acc3  += __shfl_xor(acc3, 32);

    if (half == 0) {
        const float inv = (denom > 0.f) ? (1.0f / denom) : 0.f;
        unsigned short* sx = sxb + (size_t)wid * FF + hd64 + t4;
        const ushort4 sr = *(const ushort4*)sx;
        ushort4 o;
        o.x = f2bf(fmaf(acc0, inv, bf2f(sr.x)));
        o.y = f2bf(fmaf(acc1, inv, bf2f(sr.y)));
        o.z = f2bf(fmaf(acc2, inv, bf2f(sr.z)));
        o.w = f2bf(fmaf(acc3, inv, bf2f(sr.w)));
        *(ushort4*)sx = o;
    }
}

// ---------------- GEMM2 (MFMA) + epilogue ------------------------------------
__global__ __launch_bounds__(256) void k_out(
    const unsigned short* __restrict__ nb, const unsigned short* __restrict__ sxb,
    const unsigned short* __restrict__ Wp2, float* __restrict__ out)
{
    const int wave = threadIdx.x >> 6, lane = threadIdx.x & 63;
    const int row0 = blockIdx.x * 32;
    const int arow = row0 + (lane & 31);
    const int khalf = lane >> 5;
    const int cf = wave;

    f32x16 gacc, facc;
    #pragma unroll
    for (int r = 0; r < 16; ++r) { gacc[r] = 0.f; facc[r] = 0.f; }

    #pragma unroll
    for (int ks = 0; ks < 8; ++ks) {
        bf16x8 an = *(const bf16x8*)(nb  + (size_t)arow * FF + ks * 16 + khalf * 8);
        bf16x8 ax = *(const bf16x8*)(sxb + (size_t)arow * FF + ks * 16 + khalf * 8);
        bf16x8 b0 = *(const bf16x8*)(Wp2 + (((0 * 4 + cf) * 8 + ks) << 9) + (lane << 3));
        bf16x8 b1 = *(const bf16x8*)(Wp2 + (((1 * 4 + cf) * 8 + ks) << 9) + (lane << 3));
        bf16x8 b2 = *(const bf16x8*)(Wp2 + (((2 * 4 + cf) * 8 + ks) << 9) + (lane << 3));
        gacc = __builtin_amdgcn_mfma_f32_32x32x16_bf16(an, b0, gacc, 0, 0, 0);
        gacc = __builtin_amdgcn_mfma_f32_32x32x16_bf16(ax, b1, gacc, 0, 0, 0);
        facc = __builtin_amdgcn_mfma_f32_32x32x16_bf16(ax, b2, facc, 0, 0, 0);
    }

    const int col = cf * 32 + (lane & 31);
    #pragma unroll
    for (int r = 0; r < 16; ++r) {
        const int rr = row0 + (r & 3) + 8 * (r >> 2) + 4 * (lane >> 5);
        const float g  = 1.0f / (1.0f + __expf(-gacc[r]));
        const float e2 = __expf(2.0f * facc[r]);
        const float fv = (e2 - 1.0f) / (e2 + 1.0f);     // tanh
        const float nv = bf2f(nb[(size_t)rr * FF + col]);
        out[(size_t)rr * FF + col] = g * fv + (1.0f - g) * nv;
    }
}

extern "C" void kernel_launch(void* const* d_in, const int* in_sizes, int n_in,
                              void* d_out, int out_size, void* d_ws, size_t ws_size,
                              hipStream_t stream) {
    const float* nodes = (const float*)d_in[0];
    const int*   ei    = (const int*)d_in[1];
    const int*   esrc  = ei;        // edge_index[0]
    const int*   edst  = ei + EE;   // edge_index[1]
    const float* Wq = (const float*)d_in[2];
    const float* bq = (const float*)d_in[3];
    const float* Wk = (const float*)d_in[4];
    const float* bk = (const float*)d_in[5];
    const float* Wv = (const float*)d_in[6];
    const float* bv = (const float*)d_in[7];
    const float* Ws = (const float*)d_in[8];
    const float* bs = (const float*)d_in[9];
    const float* Wg = (const float*)d_in[10];
    const float* Wf = (const float*)d_in[11];
    float* out = (float*)d_out;

    // ws layout:
    //   qb  : NN*128*2 = 25.6MB
    //   kvb : NN*256*2 = 51.2MB   (k|v interleaved per 16B chunk, gather target)
    //   sxb : NN*128*2 = 25.6MB   (skip -> x)
    //   nb  : NN*128*2 = 25.6MB   (nodes bf16)
    //   Wp  : 65536*2; Wp2 : 49152*2; bias : 512*4
    //   count: 0.4MB; srclist: NN*CAP*4 = 24MB        total ~153MB
    char* wsb = (char*)d_ws;
    unsigned short* qb   = (unsigned short*)wsb;
    unsigned short* kvb  = qb + (size_t)NN * 128;
    unsigned short* sxb  = kvb + (size_t)NN * 256;
    unsigned short* nb   = sxb + (size_t)NN * 128;
    unsigned short* Wp   = nb + (size_t)NN * 128;
    unsigned short* Wp2  = Wp + 65536;
    float* bias  = (float*)(Wp2 + 49152);
    int* count   = (int*)(bias + 512);
    int* srclist = count + NN;

    hipMemsetAsync(count, 0, NN * sizeof(int), stream);

    k_f1<<<BUILD_BLOCKS + NB_BLOCKS + PREP_BLOCKS, 256, 0, stream>>>(
        esrc, edst, count, srclist,
        Wq, Wk, Wv, Ws, Wg, Wf, bq, bk, bv, bs, Wp, Wp2, bias,
        nodes, nb);
    k_qkvs<<<NN / 32, 256, 0, stream>>>(nb, Wp, bias, qb, kvb, sxb);
    k_attn<<<(NN * 64) / 256, 256, 0, stream>>>(qb, kvb, sxb, count, srclist);
    k_out<<<NN / 32, 256, 0, stream>>>(nb, sxb, Wp2, out);
}